// Round 7
// baseline (1630.988 us; speedup 1.0000x reference)
//
#include <hip/hip_runtime.h>
#include <hip/hip_bf16.h>
#include <math.h>

#define BB 16
#define TT 360
#define VV 25
#define NN 9000
#define EE 72000
#define HH 128
#define RR (NN * BB)     // 144000 rows total
#define CROWS 18000      // rows per chunk (9000 nodes x 2 batches)
#define NT2 1128         // 8 chunks x 141 tiles
#define NPART0 563       // partial-stats blocks for k_mm2 (L0)
#define NCLSS 12
#define EPSB 1e-5f

// chunked activation layout: row R(n,b) = (b>>1)*18000 + n*2 + (b&1)

typedef short short8 __attribute__((ext_vector_type(8)));
typedef float float16v __attribute__((ext_vector_type(16)));
typedef unsigned short ushort_t;

__device__ __forceinline__ float bf2f(ushort_t u) {
    union { unsigned i; float f; } w;
    w.i = ((unsigned)u) << 16;
    return w.f;
}
__device__ __forceinline__ ushort_t f2bf(float f) {
    union { float f; unsigned i; } w;
    w.f = f;
    unsigned r = (w.i + 0x7FFF + ((w.i >> 16) & 1)) >> 16;  // RNE
    return (ushort_t)r;
}

// ---------------- graph preprocessing ----------------

__global__ void k_count(const int* __restrict__ ei, int* __restrict__ counts) {
    int e = blockIdx.x * 256 + threadIdx.x;
    if (e < EE) atomicAdd(&counts[ei[EE + e]], 1);
}

__global__ void k_dinv(const int* __restrict__ counts, float* __restrict__ dinv) {
    int n = blockIdx.x * 256 + threadIdx.x;
    if (n < NN) dinv[n] = rsqrtf((float)(counts[n] + 1));
}

__global__ void k_scan(const int* __restrict__ counts, int* __restrict__ rowptr) {
    __shared__ int part[1024];
    int t = threadIdx.x;
    int base = t * 9;
    int loc[9];
    int s = 0;
#pragma unroll
    for (int i = 0; i < 9; i++) {
        int idx = base + i;
        int v = (idx < NN) ? counts[idx] : 0;
        loc[i] = s;
        s += v;
    }
    part[t] = s;
    __syncthreads();
    for (int d = 1; d < 1024; d <<= 1) {
        int v = (t >= d) ? part[t - d] : 0;
        __syncthreads();
        part[t] += v;
        __syncthreads();
    }
    int excl = (t == 0) ? 0 : part[t - 1];
#pragma unroll
    for (int i = 0; i < 9; i++) {
        int idx = base + i;
        if (idx < NN) rowptr[idx] = excl + loc[i];
    }
    if (t == 1023) rowptr[NN] = part[1023];
}

__global__ void k_fill(const int* __restrict__ ei, const int* __restrict__ rowptr,
                       int* __restrict__ cursor, const float* __restrict__ dinv,
                       int* __restrict__ csr_src, float* __restrict__ csr_coef) {
    int e = blockIdx.x * 256 + threadIdx.x;
    if (e >= EE) return;
    int s = ei[e], d = ei[EE + e];
    int slot = rowptr[d] + atomicAdd(&cursor[d], 1);
    csr_src[slot] = s;
    csr_coef[slot] = dinv[s] * dinv[d];
}

// pre-convert the 11 layer weight matrices to bf16 W^T images: Wbf[l][c*128+k]
__global__ void k_wcvt(const float* __restrict__ sW, const float* __restrict__ mW,
                       const float* __restrict__ aW, ushort_t* __restrict__ Wbf) {
    int idx = blockIdx.x * 256 + threadIdx.x;
    if (idx >= 11 * 16384) return;
    int l = idx >> 14, r = idx & 16383;
    int k = r >> 7, c = r & 127;
    const float* src = (l < 2) ? sW + (size_t)l * 16384
                               : ((l == 2) ? mW : aW + (size_t)(l - 3) * 16384);
    Wbf[(size_t)l * 16384 + c * 128 + k] = f2bf(src[k * 128 + c]);
}

// ---------------- L0 propagation of raw x (2 channels) ----------------
__global__ void k_prop2(const float* __restrict__ x, float* __restrict__ P0,
                        const int* __restrict__ rowptr, const int* __restrict__ csr_src,
                        const float* __restrict__ coef, const float* __restrict__ dinv) {
    int n = blockIdx.x * 256 + threadIdx.x;
    if (n >= NN) return;
    int b = blockIdx.y;
    const float* xb = x + (size_t)b * NN * 2;
    float d2 = dinv[n] * dinv[n];
    float a0 = d2 * xb[2 * n], a1 = d2 * xb[2 * n + 1];
    int beg = rowptr[n], end = rowptr[n + 1];
    for (int j = beg; j < end; j++) {
        int s = csr_src[j];
        float cf = coef[j];
        a0 += cf * xb[2 * s];
        a1 += cf * xb[2 * s + 1];
    }
    float* Pb = P0 + (size_t)(n * BB + b) * 2;
    Pb[0] = a0;
    Pb[1] = a1;
}

// L0 matmul (K=2), writes chunked layout, fused BN partial stats pS[c][part].
__global__ void __launch_bounds__(256) k_mm2(const float* __restrict__ P0,
                                             ushort_t* __restrict__ A,
                                             const float* __restrict__ W,
                                             const float* __restrict__ bias,
                                             float* __restrict__ pS1, float* __restrict__ pS2) {
    __shared__ float L1[256][8], L2[256][8];
    int t = threadIdx.x;
    int cg = t & 15, c8 = cg * 8;
    float wv0[8], wv1[8], bv[8];
#pragma unroll
    for (int j = 0; j < 8; j++) {
        wv0[j] = W[c8 + j];
        wv1[j] = W[HH + c8 + j];
        bv[j] = bias[c8 + j];
    }
    float s1[8], s2[8];
#pragma unroll
    for (int j = 0; j < 8; j++) { s1[j] = 0.f; s2[j] = 0.f; }
    for (int idx = blockIdx.x * 256 + t; idx < RR * 16; idx += gridDim.x * 256) {
        int Rr = idx >> 4;
        int q = Rr / CROWS;
        int rr = Rr - q * CROWS;
        int n = rr >> 1;
        int b = q * 2 + (rr & 1);
        float p0 = P0[((size_t)n * BB + b) * 2], p1 = P0[((size_t)n * BB + b) * 2 + 1];
        short8 o;
#pragma unroll
        for (int j = 0; j < 8; j++) {
            float v = p0 * wv0[j] + p1 * wv1[j] + bv[j];
            s1[j] += v;
            s2[j] += v * v;
            o[j] = (short)f2bf(v);
        }
        *(short8*)(A + (size_t)Rr * HH + c8) = o;
    }
#pragma unroll
    for (int j = 0; j < 8; j++) { L1[t][j] = s1[j]; L2[t][j] = s2[j]; }
    __syncthreads();
    if (t < 16) {
#pragma unroll
        for (int g = 1; g < 16; g++)
#pragma unroll
            for (int j = 0; j < 8; j++) {
                s1[j] = (g == 1 ? L1[t][j] : s1[j]) + L1[t + 16 * g][j];
                s2[j] = (g == 1 ? L2[t][j] : s2[j]) + L2[t + 16 * g][j];
            }
#pragma unroll
        for (int j = 0; j < 8; j++) {
            pS1[(size_t)(t * 8 + j) * NPART0 + blockIdx.x] = s1[j];
            pS2[(size_t)(t * 8 + j) * NPART0 + blockIdx.x] = s2[j];
        }
    }
}

// ---------------- FUSED layer: gather+BN+ReLU -> LDS -> MFMA -> A + stats ----
// chunked: blockIdx = chunk (&7, XCD-routed) + tile (>>3). 64 nodes x 2 batches/tile.
__global__ void __launch_bounds__(256) k_layer(const ushort_t* __restrict__ h,
                                               ushort_t* __restrict__ A,
                                               const ushort_t* __restrict__ Wbf,
                                               const float* __restrict__ bias,
                                               const int* __restrict__ rowptr,
                                               const int* __restrict__ csr_src,
                                               const float* __restrict__ coef,
                                               const float* __restrict__ dinv,
                                               const float* __restrict__ scale,
                                               const float* __restrict__ shiftv, int shn,
                                               float* __restrict__ pS1,
                                               float* __restrict__ pS2) {
    __shared__ ushort_t pt[128 * 128];          // swizzled P tile, 32 KB
    __shared__ float rb1[4][128], rb2[4][128];  // 4 KB stats reduction
    int t = threadIdx.x;
    int chunk = blockIdx.x & 7;
    int tile = blockIdx.x >> 3;
    int row0 = tile * 128;
    int vrows = CROWS - row0;
    if (vrows > 128) vrows = 128;
    int vnodes = vrows >> 1;
    const ushort_t* hb = h + (size_t)chunk * CROWS * HH;

    int ng = t >> 5, bi = (t >> 4) & 1, cg = t & 15, c8 = cg * 8;
    float sc[8], sh[8];
#pragma unroll
    for (int j = 0; j < 8; j++) {
        sc[j] = scale[c8 + j];
        sh[j] = shiftv[c8 + j];
    }
    // ---- phase 1: gather 8 nodes per 32-thread group into LDS (swizzled) ----
    for (int i = 0; i < 8; i++) {
        int nl = ng * 8 + i;
        short8 o;
        if (nl < vnodes) {
            int n = tile * 64 + nl;
            int pn = n + shn;
            if (pn >= NN) pn -= NN;
            float d2 = dinv[n] * dinv[n];
            float acc[8];
            {
                short8 v = *(const short8*)(hb + ((size_t)pn * 2 + bi) * HH + c8);
#pragma unroll
                for (int j = 0; j < 8; j++) {
                    float f = bf2f((ushort_t)v[j]) * sc[j] + sh[j];
                    acc[j] = d2 * fmaxf(f, 0.f);
                }
            }
            int beg = rowptr[n], end = rowptr[n + 1];
            for (int e = beg; e < end; e++) {
                int s = csr_src[e];
                float cf = coef[e];
                int ps = s + shn;
                if (ps >= NN) ps -= NN;
                short8 v = *(const short8*)(hb + ((size_t)ps * 2 + bi) * HH + c8);
#pragma unroll
                for (int j = 0; j < 8; j++) {
                    float f = bf2f((ushort_t)v[j]) * sc[j] + sh[j];
                    acc[j] += cf * fmaxf(f, 0.f);
                }
            }
#pragma unroll
            for (int j = 0; j < 8; j++) o[j] = (short)f2bf(acc[j]);
        } else {
#pragma unroll
            for (int j = 0; j < 8; j++) o[j] = 0;
        }
        int row = nl * 2 + bi;
        *(short8*)(pt + row * 128 + ((cg ^ (row & 15)) * 8)) = o;
    }
    __syncthreads();
    // ---- phase 2: MFMA (A-frags from LDS, B-frags from global W^T bf16) ----
    int w = t >> 6, l = t & 63;
    int rw = w >> 1, cw = w & 1;
    int lr = l & 31, hi = l >> 5;
    float16v acc2[2][2];
#pragma unroll
    for (int rt = 0; rt < 2; rt++)
#pragma unroll
        for (int ct = 0; ct < 2; ct++) acc2[rt][ct] = (float16v)(0.0f);
    const ushort_t* Wc0 = Wbf + (size_t)(cw * 64 + lr) * HH;
    const ushort_t* Wc1 = Wbf + (size_t)(cw * 64 + 32 + lr) * HH;
#pragma unroll
    for (int ks = 0; ks < 8; ks++) {
        int koff = ks * 16 + hi * 8;
        int chx = (ks * 2 + hi) ^ (lr & 15);
        short8 a0 = *(const short8*)(pt + (rw * 64 + lr) * 128 + chx * 8);
        short8 a1 = *(const short8*)(pt + (rw * 64 + 32 + lr) * 128 + chx * 8);
        short8 b0 = *(const short8*)(Wc0 + koff);
        short8 b1 = *(const short8*)(Wc1 + koff);
        acc2[0][0] = __builtin_amdgcn_mfma_f32_32x32x16_bf16(a0, b0, acc2[0][0], 0, 0, 0);
        acc2[0][1] = __builtin_amdgcn_mfma_f32_32x32x16_bf16(a0, b1, acc2[0][1], 0, 0, 0);
        acc2[1][0] = __builtin_amdgcn_mfma_f32_32x32x16_bf16(a1, b0, acc2[1][0], 0, 0, 0);
        acc2[1][1] = __builtin_amdgcn_mfma_f32_32x32x16_bf16(a1, b1, acc2[1][1], 0, 0, 0);
    }
    // ---- epilogue: bias, stats, store bf16 (guard tail rows) ----
    float bv[2] = {bias[cw * 64 + lr], bias[cw * 64 + 32 + lr]};
    float s1a[2] = {0.f, 0.f}, s2a[2] = {0.f, 0.f};
    size_t gbase = (size_t)chunk * CROWS + row0;
#pragma unroll
    for (int rt = 0; rt < 2; rt++)
#pragma unroll
        for (int ct = 0; ct < 2; ct++) {
            int c = cw * 64 + ct * 32 + lr;
#pragma unroll
            for (int g = 0; g < 16; g++) {
                int row = rw * 64 + rt * 32 + (g & 3) + 8 * (g >> 2) + 4 * hi;
                if (row < vrows) {
                    float v = acc2[rt][ct][g] + bv[ct];
                    s1a[ct] += v;
                    s2a[ct] += v * v;
                    A[(gbase + row) * HH + c] = f2bf(v);
                }
            }
        }
    int slot = rw * 2 + hi;
#pragma unroll
    for (int ct = 0; ct < 2; ct++) {
        int cidx = cw * 64 + ct * 32 + lr;
        rb1[slot][cidx] = s1a[ct];
        rb2[slot][cidx] = s2a[ct];
    }
    __syncthreads();
    if (t < 128) {
        float a1 = rb1[0][t] + rb1[1][t] + rb1[2][t] + rb1[3][t];
        float a2 = rb2[0][t] + rb2[1][t] + rb2[2][t] + rb2[3][t];
        pS1[(size_t)t * NT2 + blockIdx.x] = a1;  // transposed: [channel][block]
        pS2[(size_t)t * NT2 + blockIdx.x] = a2;
    }
}

// finalize BN affine from transposed partials: one block per channel
__global__ void __launch_bounds__(256) k_bnfin(const float* __restrict__ pS1,
                                               const float* __restrict__ pS2, int npart,
                                               const float* __restrict__ g,
                                               const float* __restrict__ be,
                                               float* __restrict__ scale,
                                               float* __restrict__ shiftv) {
    __shared__ float R1[256], R2[256];
    int c = blockIdx.x;
    int t = threadIdx.x;
    const float* p1 = pS1 + (size_t)c * npart;
    const float* p2 = pS2 + (size_t)c * npart;
    float s1 = 0.f, s2 = 0.f;
    for (int i = t; i < npart; i += 256) {
        s1 += p1[i];
        s2 += p2[i];
    }
    R1[t] = s1;
    R2[t] = s2;
    __syncthreads();
    for (int d = 128; d > 0; d >>= 1) {
        if (t < d) {
            R1[t] += R1[t + d];
            R2[t] += R2[t + d];
        }
        __syncthreads();
    }
    if (t == 0) {
        float inv = 1.0f / (float)RR;
        float mu = R1[0] * inv;
        float var = R2[0] * inv - mu * mu;
        float sc = g[c] * rsqrtf(var + EPSB);
        scale[c] = sc;
        shiftv[c] = be[c] - mu * sc;
    }
}

// fused BN-affine + ReLU + mean-pool (per head), chunked layout reads
__global__ void __launch_bounds__(256) k_relu_pool(const ushort_t* __restrict__ A,
                                                   const float* __restrict__ scale,
                                                   const float* __restrict__ shiftv,
                                                   float* __restrict__ pooled) {
    __shared__ float L[256][8];
    int t = threadIdx.x;
    int b = blockIdx.y;
    int n0 = blockIdx.x * 250;
    int ng = t >> 4, c8 = (t & 15) * 8;
    float sc[8], sh[8];
#pragma unroll
    for (int j = 0; j < 8; j++) {
        sc[j] = scale[c8 + j];
        sh[j] = shiftv[c8 + j];
    }
    const ushort_t* Ab = A + ((size_t)(b >> 1) * CROWS + (b & 1)) * HH;
    float acc[8];
#pragma unroll
    for (int j = 0; j < 8; j++) acc[j] = 0.f;
    for (int n = n0 + ng; n < n0 + 250; n += 16) {
        short8 v = *(const short8*)(Ab + (size_t)n * 2 * HH + c8);
#pragma unroll
        for (int j = 0; j < 8; j++) {
            float f = bf2f((ushort_t)v[j]) * sc[j] + sh[j];
            acc[j] += fmaxf(f, 0.f);
        }
    }
#pragma unroll
    for (int j = 0; j < 8; j++) L[t][j] = acc[j];
    __syncthreads();
    if (ng == 0) {
#pragma unroll
        for (int g = 1; g < 16; g++)
#pragma unroll
            for (int j = 0; j < 8; j++) acc[j] += L[t + 16 * g][j];
#pragma unroll
        for (int j = 0; j < 8; j++) atomicAdd(&pooled[b * HH + t * 8 + j], acc[j]);
    }
}

// all 9 heads: linear + log_softmax
__global__ void __launch_bounds__(192) k_head_all(const float* __restrict__ pooled,
                                                  const float* __restrict__ main_Wf,
                                                  const float* __restrict__ main_bf,
                                                  const float* __restrict__ aux_Wf,
                                                  const float* __restrict__ aux_bf,
                                                  float* __restrict__ out) {
    int hd = blockIdx.x;
    const float* Wf = hd ? aux_Wf + (size_t)(hd - 1) * HH * NCLSS : main_Wf;
    const float* bf = hd ? aux_bf + (hd - 1) * NCLSS : main_bf;
    const float* pl = pooled + (size_t)hd * BB * HH;
    __shared__ float z[BB][NCLSS];
    __shared__ float lse[BB];
    int t = threadIdx.x;
    int b = t / NCLSS, j = t % NCLSS;
    if (t < BB * NCLSS) {
        float acc = bf[j];
        const float invn = 1.0f / NN;
        for (int c = 0; c < HH; c++) acc += pl[b * HH + c] * invn * Wf[c * NCLSS + j];
        z[b][j] = acc;
    }
    __syncthreads();
    if (t < BB) {
        float m = -1e30f;
        for (int j2 = 0; j2 < NCLSS; j2++) m = fmaxf(m, z[t][j2]);
        float s = 0.f;
        for (int j2 = 0; j2 < NCLSS; j2++) s += expf(z[t][j2] - m);
        lse[t] = m + logf(s);
    }
    __syncthreads();
    if (t < BB * NCLSS) {
        float* o = hd ? out + BB * NCLSS + ((size_t)b * 8 + (hd - 1)) * NCLSS + j
                      : out + b * NCLSS + j;
        *o = z[b][j] - lse[b];
    }
}

// ---------------- host ----------------

extern "C" void kernel_launch(void* const* d_in, const int* in_sizes, int n_in, void* d_out,
                              int out_size, void* d_ws, size_t ws_size, hipStream_t stream) {
    const float* x = (const float*)d_in[0];
    const int* ei = (const int*)d_in[1];
    const float* W_in = (const float*)d_in[2];
    const float* b_in = (const float*)d_in[3];
    const float* g_in = (const float*)d_in[4];
    const float* be_in = (const float*)d_in[5];
    const float* shared_W = (const float*)d_in[6];
    const float* shared_b = (const float*)d_in[7];
    const float* shared_g = (const float*)d_in[8];
    const float* shared_be = (const float*)d_in[9];
    const float* main_Wg = (const float*)d_in[10];
    const float* main_bg = (const float*)d_in[11];
    const float* main_g = (const float*)d_in[12];
    const float* main_be = (const float*)d_in[13];
    const float* main_Wf = (const float*)d_in[14];
    const float* main_bf = (const float*)d_in[15];
    const float* aux_Wg = (const float*)d_in[16];
    const float* aux_bg = (const float*)d_in[17];
    const float* aux_g = (const float*)d_in[18];
    const float* aux_be = (const float*)d_in[19];
    const float* aux_Wf = (const float*)d_in[20];
    const float* aux_bf = (const float*)d_in[21];
    float* out = (float*)d_out;

    char* w = (char*)d_ws;
    const size_t BIG = (size_t)RR * HH * 2;
    ushort_t* U = (ushort_t*)w;  w += BIG;
    ushort_t* V = (ushort_t*)w;  w += BIG;
    float* P0 = (float*)w;       w += (size_t)RR * 2 * 4;
    ushort_t* Wbf = (ushort_t*)w; w += (size_t)11 * 16384 * 2;
    int* csr_src = (int*)w;      w += EE * 4;
    float* csr_coef = (float*)w; w += EE * 4;
    int* counts = (int*)w;       w += NN * 4;
    int* cursor = (int*)w;       w += NN * 4;
    float* dinv = (float*)w;     w += NN * 4;
    int* rowptr = (int*)w;       w += 36016;
    float* pS1 = (float*)w;      w += (size_t)HH * NT2 * 4;
    float* pS2 = (float*)w;      w += (size_t)HH * NT2 * 4;
    float* pooled = (float*)w;   w += 9 * BB * HH * 4;
    float* tscale = (float*)w;   w += 512;
    float* tshift = (float*)w;   w += 512;
    float* hscale = (float*)w;   w += 512;
    float* hshift = (float*)w;   w += 512;

    hipMemsetAsync(counts, 0, 2 * NN * 4, stream);
    hipMemsetAsync(pooled, 0, 9 * BB * HH * 4, stream);

    k_count<<<(EE + 255) / 256, 256, 0, stream>>>(ei, counts);
    k_dinv<<<(NN + 255) / 256, 256, 0, stream>>>(counts, dinv);
    k_scan<<<1, 1024, 0, stream>>>(counts, rowptr);
    k_fill<<<(EE + 255) / 256, 256, 0, stream>>>(ei, rowptr, cursor, dinv, csr_src, csr_coef);
    k_wcvt<<<(11 * 16384 + 255) / 256, 256, 0, stream>>>(shared_W, main_Wg, aux_Wg, Wbf);

    // L0
    {
        dim3 g((NN + 255) / 256, BB);
        k_prop2<<<g, 256, 0, stream>>>(x, P0, rowptr, csr_src, csr_coef, dinv);
        k_mm2<<<NPART0, 256, 0, stream>>>(P0, U, W_in, b_in, pS1, pS2);
        k_bnfin<<<HH, 256, 0, stream>>>(pS1, pS2, NPART0, g_in, be_in, tscale, tshift);
    }

    // shared trunk layers (fused prop+matmul)
    ushort_t* hcur = U;
    ushort_t* hnext = V;
    for (int l = 0; l < 2; l++) {
        k_layer<<<NT2, 256, 0, stream>>>(hcur, hnext, Wbf + (size_t)l * 16384,
                                         shared_b + l * HH, rowptr, csr_src, csr_coef, dinv,
                                         tscale, tshift, 0, pS1, pS2);
        k_bnfin<<<HH, 256, 0, stream>>>(pS1, pS2, NT2, shared_g + l * HH, shared_be + l * HH,
                                        tscale, tshift);
        ushort_t* tmp = hcur; hcur = hnext; hnext = tmp;
    }

    // heads
    for (int hd = 0; hd < 9; hd++) {
        int shift = hd * 1000;
        const ushort_t* Wg = Wbf + (size_t)(2 + hd) * 16384;
        const float* bg = (hd == 0) ? main_bg : aux_bg + (hd - 1) * HH;
        const float* gg = (hd == 0) ? main_g : aux_g + (hd - 1) * HH;
        const float* be = (hd == 0) ? main_be : aux_be + (hd - 1) * HH;

        k_layer<<<NT2, 256, 0, stream>>>(hcur, hnext, Wg, bg, rowptr, csr_src, csr_coef, dinv,
                                         tscale, tshift, shift, pS1, pS2);
        k_bnfin<<<HH, 256, 0, stream>>>(pS1, pS2, NT2, gg, be, hscale, hshift);
        dim3 gp(36, BB);
        k_relu_pool<<<gp, 256, 0, stream>>>(hnext, hscale, hshift, pooled + (size_t)hd * BB * HH);
    }
    k_head_all<<<9, 192, 0, stream>>>(pooled, main_Wf, main_bf, aux_Wf, aux_bf, out);
}

// Round 8
// 1024.812 us; speedup vs baseline: 1.5915x; 1.5915x over previous
//
#include <hip/hip_runtime.h>
#include <hip/hip_bf16.h>
#include <math.h>

#define BB 16
#define TT 360
#define VV 25
#define NN 9000
#define EE 72000
#define HH 128
#define RR (NN * BB)      // 144000 rows, node-major: row = n*BB + b
#define NTILES (RR / 64)  // 2250 tiles (4 nodes x 16 batch = 64 rows) for k_layer
#define NPART0 563        // partial-stats blocks for k_mm2 (L0)
#define NCLSS 12
#define EPSB 1e-5f

typedef short short8 __attribute__((ext_vector_type(8)));
typedef float float16v __attribute__((ext_vector_type(16)));
typedef unsigned short ushort_t;

__device__ __forceinline__ float bf2f(ushort_t u) {
    union { unsigned i; float f; } w;
    w.i = ((unsigned)u) << 16;
    return w.f;
}
__device__ __forceinline__ ushort_t f2bf(float f) {
    union { float f; unsigned i; } w;
    w.f = f;
    unsigned r = (w.i + 0x7FFF + ((w.i >> 16) & 1)) >> 16;  // RNE
    return (ushort_t)r;
}

// ---------------- graph preprocessing ----------------

__global__ void k_count(const int* __restrict__ ei, int* __restrict__ counts) {
    int e = blockIdx.x * 256 + threadIdx.x;
    if (e < EE) atomicAdd(&counts[ei[EE + e]], 1);
}

__global__ void k_dinv(const int* __restrict__ counts, float* __restrict__ dinv) {
    int n = blockIdx.x * 256 + threadIdx.x;
    if (n < NN) dinv[n] = rsqrtf((float)(counts[n] + 1));
}

__global__ void k_scan(const int* __restrict__ counts, int* __restrict__ rowptr) {
    __shared__ int part[1024];
    int t = threadIdx.x;
    int base = t * 9;
    int loc[9];
    int s = 0;
#pragma unroll
    for (int i = 0; i < 9; i++) {
        int idx = base + i;
        int v = (idx < NN) ? counts[idx] : 0;
        loc[i] = s;
        s += v;
    }
    part[t] = s;
    __syncthreads();
    for (int d = 1; d < 1024; d <<= 1) {
        int v = (t >= d) ? part[t - d] : 0;
        __syncthreads();
        part[t] += v;
        __syncthreads();
    }
    int excl = (t == 0) ? 0 : part[t - 1];
#pragma unroll
    for (int i = 0; i < 9; i++) {
        int idx = base + i;
        if (idx < NN) rowptr[idx] = excl + loc[i];
    }
    if (t == 1023) rowptr[NN] = part[1023];
}

__global__ void k_fill(const int* __restrict__ ei, const int* __restrict__ rowptr,
                       int* __restrict__ cursor, const float* __restrict__ dinv,
                       int2* __restrict__ csr) {
    int e = blockIdx.x * 256 + threadIdx.x;
    if (e >= EE) return;
    int s = ei[e], d = ei[EE + e];
    int slot = rowptr[d] + atomicAdd(&cursor[d], 1);
    int2 e2;
    e2.x = s;
    e2.y = __float_as_int(dinv[s] * dinv[d]);
    csr[slot] = e2;
}

// pre-convert the 11 layer weight matrices to bf16 W^T images: Wbf[l][c*128+k]
__global__ void k_wcvt(const float* __restrict__ sW, const float* __restrict__ mW,
                       const float* __restrict__ aW, ushort_t* __restrict__ Wbf) {
    int idx = blockIdx.x * 256 + threadIdx.x;
    if (idx >= 11 * 16384) return;
    int l = idx >> 14, r = idx & 16383;
    int k = r >> 7, c = r & 127;
    const float* src = (l < 2) ? sW + (size_t)l * 16384
                               : ((l == 2) ? mW : aW + (size_t)(l - 3) * 16384);
    Wbf[(size_t)l * 16384 + c * 128 + k] = f2bf(src[k * 128 + c]);
}

// ---------------- L0 propagation of raw x (2 channels) ----------------
__global__ void k_prop2(const float* __restrict__ x, float* __restrict__ P0,
                        const int* __restrict__ rowptr, const int2* __restrict__ csr,
                        const float* __restrict__ dinv) {
    int n = blockIdx.x * 256 + threadIdx.x;
    if (n >= NN) return;
    int b = blockIdx.y;
    const float* xb = x + (size_t)b * NN * 2;
    float d2 = dinv[n] * dinv[n];
    float a0 = d2 * xb[2 * n], a1 = d2 * xb[2 * n + 1];
    int beg = rowptr[n], end = rowptr[n + 1];
    for (int j = beg; j < end; j++) {
        int2 e2 = csr[j];
        int s = e2.x;
        float cf = __int_as_float(e2.y);
        a0 += cf * xb[2 * s];
        a1 += cf * xb[2 * s + 1];
    }
    float* Pb = P0 + (size_t)(n * BB + b) * 2;
    Pb[0] = a0;
    Pb[1] = a1;
}

// L0 matmul (K=2) with fused BN partial stats, transposed partials pS[c][part].
__global__ void __launch_bounds__(256) k_mm2(const float* __restrict__ P0,
                                             ushort_t* __restrict__ A,
                                             const float* __restrict__ W,
                                             const float* __restrict__ bias,
                                             float* __restrict__ pS1, float* __restrict__ pS2) {
    __shared__ float L1[256][8], L2[256][8];
    int t = threadIdx.x;
    int cg = t & 15, c8 = cg * 8;
    float wv0[8], wv1[8], bv[8];
#pragma unroll
    for (int j = 0; j < 8; j++) {
        wv0[j] = W[c8 + j];
        wv1[j] = W[HH + c8 + j];
        bv[j] = bias[c8 + j];
    }
    float s1[8], s2[8];
#pragma unroll
    for (int j = 0; j < 8; j++) { s1[j] = 0.f; s2[j] = 0.f; }
    for (int i = blockIdx.x * 256 + t; i < RR * 16; i += gridDim.x * 256) {
        int r = i >> 4;
        float p0 = P0[2 * (size_t)r], p1 = P0[2 * (size_t)r + 1];
        short8 o;
#pragma unroll
        for (int j = 0; j < 8; j++) {
            float v = p0 * wv0[j] + p1 * wv1[j] + bv[j];
            s1[j] += v;
            s2[j] += v * v;
            o[j] = (short)f2bf(v);
        }
        *(short8*)(A + (size_t)r * HH + c8) = o;
    }
#pragma unroll
    for (int j = 0; j < 8; j++) { L1[t][j] = s1[j]; L2[t][j] = s2[j]; }
    __syncthreads();
    if (t < 16) {
#pragma unroll
        for (int g = 1; g < 16; g++)
#pragma unroll
            for (int j = 0; j < 8; j++) {
                s1[j] = (g == 1 ? L1[t][j] : s1[j]) + L1[t + 16 * g][j];
                s2[j] = (g == 1 ? L2[t][j] : s2[j]) + L2[t + 16 * g][j];
            }
#pragma unroll
        for (int j = 0; j < 8; j++) {
            pS1[(size_t)(t * 8 + j) * NPART0 + blockIdx.x] = s1[j];
            pS2[(size_t)(t * 8 + j) * NPART0 + blockIdx.x] = s2[j];
        }
    }
}

// ---------------- FUSED layer: gather+BN+ReLU -> LDS -> MFMA -> A + stats ----
// 64-row tiles (4 nodes x 16 batches), 2250 blocks, block-uniform gather.
__global__ void __launch_bounds__(256) k_layer(const ushort_t* __restrict__ h,
                                               ushort_t* __restrict__ A,
                                               const ushort_t* __restrict__ Wbf,
                                               const float* __restrict__ bias,
                                               const int* __restrict__ rowptr,
                                               const int2* __restrict__ csr,
                                               const float* __restrict__ dinv,
                                               const float* __restrict__ scale,
                                               const float* __restrict__ shiftv, int shn,
                                               float* __restrict__ pS1,
                                               float* __restrict__ pS2) {
    __shared__ ushort_t pt[64 * 128];           // swizzled P tile, 16 KB
    __shared__ float rb1[4][128], rb2[4][128];  // 4 KB stats reduction
    int t = threadIdx.x;
    int b = t >> 4, cg = t & 15, c8 = cg * 8;
    float sc[8], sh[8];
#pragma unroll
    for (int j = 0; j < 8; j++) {
        sc[j] = scale[c8 + j];
        sh[j] = shiftv[c8 + j];
    }
    int n0 = blockIdx.x * 4;
    // ---- phase 1: propagate 4 nodes into LDS tile (block-uniform edge loops) ----
    for (int i = 0; i < 4; i++) {
        int n = n0 + i;
        int pn = n + shn;
        if (pn >= NN) pn -= NN;
        float d2 = dinv[n] * dinv[n];
        float acc[8];
        {
            short8 v = *(const short8*)(h + (size_t)(pn * BB + b) * HH + c8);
#pragma unroll
            for (int j = 0; j < 8; j++) {
                float f = bf2f((ushort_t)v[j]) * sc[j] + sh[j];
                acc[j] = d2 * fmaxf(f, 0.f);
            }
        }
        int beg = rowptr[n], end = rowptr[n + 1];
        for (int e = beg; e < end; e++) {
            int2 e2 = csr[e];
            int s = e2.x;
            float cf = __int_as_float(e2.y);
            int ps = s + shn;
            if (ps >= NN) ps -= NN;
            short8 v = *(const short8*)(h + (size_t)(ps * BB + b) * HH + c8);
#pragma unroll
            for (int j = 0; j < 8; j++) {
                float f = bf2f((ushort_t)v[j]) * sc[j] + sh[j];
                acc[j] += cf * fmaxf(f, 0.f);
            }
        }
        short8 o;
#pragma unroll
        for (int j = 0; j < 8; j++) o[j] = (short)f2bf(acc[j]);
        int row = i * 16 + b;  // row&15 == b
        *(short8*)(pt + row * 128 + ((cg ^ b) * 8)) = o;
    }
    __syncthreads();
    // ---- phase 2: MFMA (A-frags from LDS, B-frags from global W^T bf16) ----
    int w = t >> 6, l = t & 63;
    int rw = w >> 1, cw = w & 1;  // wave -> 32-row half x 64-col half
    int lr = l & 31, hi = l >> 5;
    float16v acc2[2];
#pragma unroll
    for (int ct = 0; ct < 2; ct++) acc2[ct] = (float16v)(0.0f);
    const ushort_t* Wc0 = Wbf + (size_t)(cw * 64 + lr) * HH;
    const ushort_t* Wc1 = Wbf + (size_t)(cw * 64 + 32 + lr) * HH;
#pragma unroll
    for (int ks = 0; ks < 8; ks++) {
        int koff = ks * 16 + hi * 8;
        int chx = (ks * 2 + hi) ^ (lr & 15);
        short8 a0 = *(const short8*)(pt + (rw * 32 + lr) * 128 + chx * 8);
        short8 b0 = *(const short8*)(Wc0 + koff);
        short8 b1 = *(const short8*)(Wc1 + koff);
        acc2[0] = __builtin_amdgcn_mfma_f32_32x32x16_bf16(a0, b0, acc2[0], 0, 0, 0);
        acc2[1] = __builtin_amdgcn_mfma_f32_32x32x16_bf16(a0, b1, acc2[1], 0, 0, 0);
    }
    // ---- epilogue: bias, stats, store bf16 ----
    float bv[2] = {bias[cw * 64 + lr], bias[cw * 64 + 32 + lr]};
    float s1a[2] = {0.f, 0.f}, s2a[2] = {0.f, 0.f};
    size_t rbase = (size_t)blockIdx.x * 64;
#pragma unroll
    for (int ct = 0; ct < 2; ct++) {
        int c = cw * 64 + ct * 32 + lr;
#pragma unroll
        for (int g = 0; g < 16; g++) {
            int row = rw * 32 + (g & 3) + 8 * (g >> 2) + 4 * hi;
            float v = acc2[ct][g] + bv[ct];
            s1a[ct] += v;
            s2a[ct] += v * v;
            A[(rbase + row) * HH + c] = f2bf(v);
        }
    }
    int slot = rw * 2 + hi;
#pragma unroll
    for (int ct = 0; ct < 2; ct++) {
        int cidx = cw * 64 + ct * 32 + lr;
        rb1[slot][cidx] = s1a[ct];
        rb2[slot][cidx] = s2a[ct];
    }
    __syncthreads();
    if (t < 128) {
        float a1 = rb1[0][t] + rb1[1][t] + rb1[2][t] + rb1[3][t];
        float a2 = rb2[0][t] + rb2[1][t] + rb2[2][t] + rb2[3][t];
        pS1[(size_t)t * NTILES + blockIdx.x] = a1;  // transposed: [channel][tile]
        pS2[(size_t)t * NTILES + blockIdx.x] = a2;
    }
}

// finalize BN affine from transposed partials: one block per channel, coalesced rows
__global__ void __launch_bounds__(256) k_bnfin(const float* __restrict__ pS1,
                                               const float* __restrict__ pS2, int npart,
                                               const float* __restrict__ g,
                                               const float* __restrict__ be,
                                               float* __restrict__ scale,
                                               float* __restrict__ shiftv) {
    __shared__ float R1[256], R2[256];
    int c = blockIdx.x;
    int t = threadIdx.x;
    const float* p1 = pS1 + (size_t)c * npart;
    const float* p2 = pS2 + (size_t)c * npart;
    float s1 = 0.f, s2 = 0.f;
    for (int i = t; i < npart; i += 256) {
        s1 += p1[i];
        s2 += p2[i];
    }
    R1[t] = s1;
    R2[t] = s2;
    __syncthreads();
    for (int d = 128; d > 0; d >>= 1) {
        if (t < d) {
            R1[t] += R1[t + d];
            R2[t] += R2[t + d];
        }
        __syncthreads();
    }
    if (t == 0) {
        float inv = 1.0f / (float)RR;
        float mu = R1[0] * inv;
        float var = R2[0] * inv - mu * mu;
        float sc = g[c] * rsqrtf(var + EPSB);
        scale[c] = sc;
        shiftv[c] = be[c] - mu * sc;
    }
}

// fused BN-affine + ReLU + mean-pool (per head)
__global__ void __launch_bounds__(256) k_relu_pool(const ushort_t* __restrict__ A,
                                                   const float* __restrict__ scale,
                                                   const float* __restrict__ shiftv,
                                                   float* __restrict__ pooled) {
    __shared__ float L[256][8];
    int t = threadIdx.x;
    int b = blockIdx.y;
    int n0 = blockIdx.x * 250;
    int ng = t >> 4, c8 = (t & 15) * 8;
    float sc[8], sh[8];
#pragma unroll
    for (int j = 0; j < 8; j++) {
        sc[j] = scale[c8 + j];
        sh[j] = shiftv[c8 + j];
    }
    float acc[8];
#pragma unroll
    for (int j = 0; j < 8; j++) acc[j] = 0.f;
    for (int n = n0 + ng; n < n0 + 250; n += 16) {
        short8 v = *(const short8*)(A + (size_t)(n * BB + b) * HH + c8);
#pragma unroll
        for (int j = 0; j < 8; j++) {
            float f = bf2f((ushort_t)v[j]) * sc[j] + sh[j];
            acc[j] += fmaxf(f, 0.f);
        }
    }
#pragma unroll
    for (int j = 0; j < 8; j++) L[t][j] = acc[j];
    __syncthreads();
    if (ng == 0) {
#pragma unroll
        for (int g = 1; g < 16; g++)
#pragma unroll
            for (int j = 0; j < 8; j++) acc[j] += L[t + 16 * g][j];
#pragma unroll
        for (int j = 0; j < 8; j++) atomicAdd(&pooled[b * HH + t * 8 + j], acc[j]);
    }
}

// all 9 heads: linear + log_softmax
__global__ void __launch_bounds__(192) k_head_all(const float* __restrict__ pooled,
                                                  const float* __restrict__ main_Wf,
                                                  const float* __restrict__ main_bf,
                                                  const float* __restrict__ aux_Wf,
                                                  const float* __restrict__ aux_bf,
                                                  float* __restrict__ out) {
    int hd = blockIdx.x;
    const float* Wf = hd ? aux_Wf + (size_t)(hd - 1) * HH * NCLSS : main_Wf;
    const float* bf = hd ? aux_bf + (hd - 1) * NCLSS : main_bf;
    const float* pl = pooled + (size_t)hd * BB * HH;
    __shared__ float z[BB][NCLSS];
    __shared__ float lse[BB];
    int t = threadIdx.x;
    int b = t / NCLSS, j = t % NCLSS;
    if (t < BB * NCLSS) {
        float acc = bf[j];
        const float invn = 1.0f / NN;
        for (int c = 0; c < HH; c++) acc += pl[b * HH + c] * invn * Wf[c * NCLSS + j];
        z[b][j] = acc;
    }
    __syncthreads();
    if (t < BB) {
        float m = -1e30f;
        for (int j2 = 0; j2 < NCLSS; j2++) m = fmaxf(m, z[t][j2]);
        float s = 0.f;
        for (int j2 = 0; j2 < NCLSS; j2++) s += expf(z[t][j2] - m);
        lse[t] = m + logf(s);
    }
    __syncthreads();
    if (t < BB * NCLSS) {
        float* o = hd ? out + BB * NCLSS + ((size_t)b * 8 + (hd - 1)) * NCLSS + j
                      : out + b * NCLSS + j;
        *o = z[b][j] - lse[b];
    }
}

// ---------------- host ----------------

extern "C" void kernel_launch(void* const* d_in, const int* in_sizes, int n_in, void* d_out,
                              int out_size, void* d_ws, size_t ws_size, hipStream_t stream) {
    const float* x = (const float*)d_in[0];
    const int* ei = (const int*)d_in[1];
    const float* W_in = (const float*)d_in[2];
    const float* b_in = (const float*)d_in[3];
    const float* g_in = (const float*)d_in[4];
    const float* be_in = (const float*)d_in[5];
    const float* shared_W = (const float*)d_in[6];
    const float* shared_b = (const float*)d_in[7];
    const float* shared_g = (const float*)d_in[8];
    const float* shared_be = (const float*)d_in[9];
    const float* main_Wg = (const float*)d_in[10];
    const float* main_bg = (const float*)d_in[11];
    const float* main_g = (const float*)d_in[12];
    const float* main_be = (const float*)d_in[13];
    const float* main_Wf = (const float*)d_in[14];
    const float* main_bf = (const float*)d_in[15];
    const float* aux_Wg = (const float*)d_in[16];
    const float* aux_bg = (const float*)d_in[17];
    const float* aux_g = (const float*)d_in[18];
    const float* aux_be = (const float*)d_in[19];
    const float* aux_Wf = (const float*)d_in[20];
    const float* aux_bf = (const float*)d_in[21];
    float* out = (float*)d_out;

    char* w = (char*)d_ws;
    const size_t BIG = (size_t)RR * HH * 2;
    ushort_t* U = (ushort_t*)w;  w += BIG;
    ushort_t* V = (ushort_t*)w;  w += BIG;
    float* P0 = (float*)w;       w += (size_t)RR * 2 * 4;
    ushort_t* Wbf = (ushort_t*)w; w += (size_t)11 * 16384 * 2;
    int2* csr = (int2*)w;        w += (size_t)EE * 8;
    int* counts = (int*)w;       w += NN * 4;
    int* cursor = (int*)w;       w += NN * 4;
    float* dinv = (float*)w;     w += NN * 4;
    int* rowptr = (int*)w;       w += 36016;
    float* pS1 = (float*)w;      w += (size_t)HH * NTILES * 4;
    float* pS2 = (float*)w;      w += (size_t)HH * NTILES * 4;
    float* pooled = (float*)w;   w += 9 * BB * HH * 4;
    float* tscale = (float*)w;   w += 512;
    float* tshift = (float*)w;   w += 512;
    float* hscale = (float*)w;   w += 512;
    float* hshift = (float*)w;   w += 512;

    hipMemsetAsync(counts, 0, 2 * NN * 4, stream);
    hipMemsetAsync(pooled, 0, 9 * BB * HH * 4, stream);

    k_count<<<(EE + 255) / 256, 256, 0, stream>>>(ei, counts);
    k_dinv<<<(NN + 255) / 256, 256, 0, stream>>>(counts, dinv);
    k_scan<<<1, 1024, 0, stream>>>(counts, rowptr);
    k_fill<<<(EE + 255) / 256, 256, 0, stream>>>(ei, rowptr, cursor, dinv, csr);
    k_wcvt<<<(11 * 16384 + 255) / 256, 256, 0, stream>>>(shared_W, main_Wg, aux_Wg, Wbf);

    // L0
    {
        dim3 g((NN + 255) / 256, BB);
        k_prop2<<<g, 256, 0, stream>>>(x, P0, rowptr, csr, dinv);
        k_mm2<<<NPART0, 256, 0, stream>>>(P0, U, W_in, b_in, pS1, pS2);
        k_bnfin<<<HH, 256, 0, stream>>>(pS1, pS2, NPART0, g_in, be_in, tscale, tshift);
    }

    // shared trunk layers (fused prop+matmul)
    ushort_t* hcur = U;
    ushort_t* hnext = V;
    for (int l = 0; l < 2; l++) {
        k_layer<<<NTILES, 256, 0, stream>>>(hcur, hnext, Wbf + (size_t)l * 16384,
                                            shared_b + l * HH, rowptr, csr, dinv,
                                            tscale, tshift, 0, pS1, pS2);
        k_bnfin<<<HH, 256, 0, stream>>>(pS1, pS2, NTILES, shared_g + l * HH, shared_be + l * HH,
                                        tscale, tshift);
        ushort_t* tmp = hcur; hcur = hnext; hnext = tmp;
    }

    // heads
    for (int hd = 0; hd < 9; hd++) {
        int shift = hd * 1000;
        const ushort_t* Wg = Wbf + (size_t)(2 + hd) * 16384;
        const float* bg = (hd == 0) ? main_bg : aux_bg + (hd - 1) * HH;
        const float* gg = (hd == 0) ? main_g : aux_g + (hd - 1) * HH;
        const float* be = (hd == 0) ? main_be : aux_be + (hd - 1) * HH;

        k_layer<<<NTILES, 256, 0, stream>>>(hcur, hnext, Wg, bg, rowptr, csr, dinv,
                                            tscale, tshift, shift, pS1, pS2);
        k_bnfin<<<HH, 256, 0, stream>>>(pS1, pS2, NTILES, gg, be, hscale, hshift);
        dim3 gp(36, BB);
        k_relu_pool<<<gp, 256, 0, stream>>>(hnext, hscale, hshift, pooled + (size_t)hd * BB * HH);
    }
    k_head_all<<<9, 192, 0, stream>>>(pooled, main_Wf, main_bf, aux_Wf, aux_bf, out);
}